// Round 1
// baseline (382.322 us; speedup 1.0000x reference)
//
#include <hip/hip_runtime.h>
#include <stdint.h>

#define L_SEQ   2048
#define DM      1024
#define NH      16
#define DK      64
#define BATCH   4
#define M_TOK   (BATCH * L_SEQ)   // 8192

typedef __attribute__((ext_vector_type(8))) short bf16x8;
typedef __attribute__((ext_vector_type(4))) float f32x4;

typedef __attribute__((address_space(1))) void void_g;
typedef __attribute__((address_space(3))) void void_l;

__device__ __forceinline__ unsigned short f2bf(float f) {
  unsigned int u = __builtin_bit_cast(unsigned int, f);
  u += 0x7FFFu + ((u >> 16) & 1u);
  return (unsigned short)(u >> 16);
}

// ---------------- fp32 -> bf16 convert (vectorized) ----------------
__global__ void cvt_f32_bf16(const float* __restrict__ src,
                             unsigned short* __restrict__ dst, int n4) {
  int i = blockIdx.x * blockDim.x + threadIdx.x;
  int stride = gridDim.x * blockDim.x;
  for (; i < n4; i += stride) {
    float4 v = ((const float4*)src)[i];
    ushort4 o;
    o.x = f2bf(v.x); o.y = f2bf(v.y); o.z = f2bf(v.z); o.w = f2bf(v.w);
    ((ushort4*)dst)[i] = o;
  }
}

// ---------------- bf16 GEMM: C = A @ B^T + bias ----------------
// A: [M,K] bf16 row-major (K contiguous). Bw: [N,K] bf16 (K contiguous).
// EPI 0: out bf16 [B,H,L,DK]   (Q/K projections, head-split layout)
// EPI 1: out bf16 [B,H,DK,L]   (V projection, transposed for PV reads)
// EPI 2: out fp32 [M, DM]      (final output projection)
#define BM 128
#define BN 128
#define BKK 32

template <int EPI>
__global__ __launch_bounds__(256) void gemm_bt(
    const unsigned short* __restrict__ A,
    const unsigned short* __restrict__ Bw,
    const float* __restrict__ bias,
    void* __restrict__ out, int M, int N, int K) {
  __shared__ unsigned short As[BM * BKK];
  __shared__ unsigned short Bs[BN * BKK];

  const int tidx = threadIdx.x;
  const int wid = tidx >> 6, lane = tidx & 63;
  const int wm = wid >> 1, wn = wid & 1;  // 2x2 wave grid, 64x64 per wave
  const int tm = blockIdx.y * BM, tn = blockIdx.x * BN;
  const int lr = lane & 15;
  const int lk = (lane >> 4) * 8;

  f32x4 acc[4][4];
#pragma unroll
  for (int m = 0; m < 4; ++m)
#pragma unroll
    for (int n = 0; n < 4; ++n) acc[m][n] = (f32x4)0.0f;

  for (int k0 = 0; k0 < K; k0 += BKK) {
    // stage A,B tiles: 8KB each via global_load_lds width=16
#pragma unroll
    for (int j = 0; j < 2; ++j) {
      int e0 = (wid * 2 + j) * 512;       // element base of 1KB chunk
      int e = e0 + lane * 8;
      int r = e >> 5, c = e & 31;
      __builtin_amdgcn_global_load_lds(
          (const void_g*)(A + (size_t)(tm + r) * K + k0 + c),
          (void_l*)(As + e0), 16, 0, 0);
      __builtin_amdgcn_global_load_lds(
          (const void_g*)(Bw + (size_t)(tn + r) * K + k0 + c),
          (void_l*)(Bs + e0), 16, 0, 0);
    }
    __syncthreads();

    bf16x8 a[4], b[4];
#pragma unroll
    for (int m = 0; m < 4; ++m)
      a[m] = *(const bf16x8*)&As[(wm * 64 + m * 16 + lr) * BKK + lk];
#pragma unroll
    for (int n = 0; n < 4; ++n)
      b[n] = *(const bf16x8*)&Bs[(wn * 64 + n * 16 + lr) * BKK + lk];
#pragma unroll
    for (int m = 0; m < 4; ++m)
#pragma unroll
      for (int n = 0; n < 4; ++n)
        acc[m][n] = __builtin_amdgcn_mfma_f32_16x16x32_bf16(a[m], b[n], acc[m][n], 0, 0, 0);
    __syncthreads();
  }

  // epilogue: D[row=(lane>>4)*4+j][col=lane&15]
#pragma unroll
  for (int m = 0; m < 4; ++m) {
    int row0 = tm + wm * 64 + m * 16 + (lane >> 4) * 4;
#pragma unroll
    for (int n = 0; n < 4; ++n) {
      int col = tn + wn * 64 + n * 16 + (lane & 15);
      float bc = bias[col];
#pragma unroll
      for (int jj = 0; jj < 4; ++jj) {
        float v = acc[m][n][jj] + bc;
        int R = row0 + jj;
        if (EPI == 2) {
          ((float*)out)[(size_t)R * DM + col] = v;
        } else {
          int bb = R >> 11, ll = R & (L_SEQ - 1);
          int h = col >> 6, dd = col & 63;
          if (EPI == 0)
            ((unsigned short*)out)[(((size_t)bb * NH + h) * L_SEQ + ll) * DK + dd] = f2bf(v);
          else
            ((unsigned short*)out)[(((size_t)bb * NH + h) * DK + dd) * L_SEQ + ll] = f2bf(v);
        }
      }
    }
  }
}

// ---------------- flash attention ----------------
// Q,K: [B,H,L,DK] bf16.  VT: [B,H,DK,L] bf16.  ctx out: [B*L, DM] bf16.
#define QBLK 64
#define KVBLK 64
#define KPAD 72   // +8 bf16 pad: 2-way LDS bank aliasing only (free)

__global__ __launch_bounds__(256) void flash_attn(
    const unsigned short* __restrict__ Qg,
    const unsigned short* __restrict__ Kg,
    const unsigned short* __restrict__ VTg,
    unsigned short* __restrict__ ctx) {
  __shared__ unsigned short Ks[KVBLK * KPAD];
  __shared__ unsigned short Vs[DK * KPAD];
  __shared__ unsigned short Ps[4][16 * KPAD];

  const int bh = blockIdx.x;
  const int b = bh >> 4, h = bh & 15;
  const int qbase = blockIdx.y * QBLK;
  const int tidx = threadIdx.x;
  const int wid = tidx >> 6, lane = tidx & 63;
  const int lr = lane & 15, lg = lane >> 4;
  const int lk = lg * 8;

  const size_t head = (size_t)bh * L_SEQ * DK;

  // Q fragments for this wave's 16 rows (2 K-steps of 32)
  bf16x8 qf[2];
  {
    const unsigned short* qrow = Qg + head + (size_t)(qbase + wid * 16 + lr) * DK;
    qf[0] = *(const bf16x8*)&qrow[lk];
    qf[1] = *(const bf16x8*)&qrow[32 + lk];
  }

  f32x4 oacc[4];
#pragma unroll
  for (int nt = 0; nt < 4; ++nt) oacc[nt] = (f32x4)0.0f;
  float mrow[4], lrow[4];
#pragma unroll
  for (int i = 0; i < 4; ++i) { mrow[i] = -1e30f; lrow[i] = 0.0f; }

  for (int kvb = 0; kvb < L_SEQ / KVBLK; ++kvb) {
    const int kv0 = kvb * KVBLK;
    {
      int r = tidx >> 2;             // 0..63
      int c0 = (tidx & 3) * 8;
#pragma unroll
      for (int j = 0; j < 2; ++j) {
        int c = c0 + j * 32;
        *(uint4*)&Ks[r * KPAD + c] = *(const uint4*)&Kg[head + (size_t)(kv0 + r) * DK + c];
        *(uint4*)&Vs[r * KPAD + c] = *(const uint4*)&VTg[head + (size_t)r * L_SEQ + kv0 + c];
      }
    }
    __syncthreads();

    // S = Q K^T  (4 kv sub-tiles of 16)
    f32x4 sacc[4];
#pragma unroll
    for (int n = 0; n < 4; ++n) {
      bf16x8 b0 = *(const bf16x8*)&Ks[(n * 16 + lr) * KPAD + lk];
      bf16x8 b1 = *(const bf16x8*)&Ks[(n * 16 + lr) * KPAD + 32 + lk];
      f32x4 s = (f32x4)0.0f;
      s = __builtin_amdgcn_mfma_f32_16x16x32_bf16(qf[0], b0, s, 0, 0, 0);
      s = __builtin_amdgcn_mfma_f32_16x16x32_bf16(qf[1], b1, s, 0, 0, 0);
      sacc[n] = s;
    }

    // online softmax; lane's rows are lg*4+i, cols are n*16+lr
    float pv[4][4];
#pragma unroll
    for (int i = 0; i < 4; ++i) {
      float rm = -1e30f;
#pragma unroll
      for (int n = 0; n < 4; ++n) {
        float s = sacc[n][i] * 0.125f;
        s = fminf(fmaxf(s, -100.0f), 100.0f);
        pv[n][i] = s;
        rm = fmaxf(rm, s);
      }
      rm = fmaxf(rm, __shfl_xor(rm, 1));
      rm = fmaxf(rm, __shfl_xor(rm, 2));
      rm = fmaxf(rm, __shfl_xor(rm, 4));
      rm = fmaxf(rm, __shfl_xor(rm, 8));
      float mnew = fmaxf(mrow[i], rm);
      float corr = __expf(mrow[i] - mnew);
      mrow[i] = mnew;
      float rs = 0.0f;
#pragma unroll
      for (int n = 0; n < 4; ++n) {
        float p = __expf(pv[n][i] - mnew);
        pv[n][i] = p;
        rs += p;
      }
      rs += __shfl_xor(rs, 1);
      rs += __shfl_xor(rs, 2);
      rs += __shfl_xor(rs, 4);
      rs += __shfl_xor(rs, 8);
      lrow[i] = lrow[i] * corr + rs;
#pragma unroll
      for (int nt = 0; nt < 4; ++nt) oacc[nt][i] *= corr;
    }

    // P -> LDS (bf16), per-wave region
#pragma unroll
    for (int i = 0; i < 4; ++i)
#pragma unroll
      for (int n = 0; n < 4; ++n)
        Ps[wid][(lg * 4 + i) * KPAD + n * 16 + lr] = f2bf(pv[n][i]);
    __syncthreads();

    // O += P V   (A = P[16x64], B via VT rows)
#pragma unroll
    for (int ks = 0; ks < 2; ++ks) {
      bf16x8 pa = *(const bf16x8*)&Ps[wid][lr * KPAD + ks * 32 + lk];
#pragma unroll
      for (int nt = 0; nt < 4; ++nt) {
        bf16x8 vb = *(const bf16x8*)&Vs[(nt * 16 + lr) * KPAD + ks * 32 + lk];
        oacc[nt] = __builtin_amdgcn_mfma_f32_16x16x32_bf16(pa, vb, oacc[nt], 0, 0, 0);
      }
    }
    __syncthreads();
  }

  // normalize + write ctx (bf16) in [token, feature] layout
  const int qrow0 = qbase + wid * 16 + lg * 4;
#pragma unroll
  for (int i = 0; i < 4; ++i) {
    float inv = 1.0f / lrow[i];
    size_t rowoff = ((size_t)b * L_SEQ + (qrow0 + i)) * DM + h * DK;
#pragma unroll
    for (int nt = 0; nt < 4; ++nt)
      ctx[rowoff + nt * 16 + lr] = f2bf(oacc[nt][i] * inv);
  }
}

// ---------------- launch ----------------
extern "C" void kernel_launch(void* const* d_in, const int* in_sizes, int n_in,
                              void* d_out, int out_size, void* d_ws, size_t ws_size,
                              hipStream_t stream) {
  (void)in_sizes; (void)n_in; (void)out_size; (void)ws_size;
  const float* x  = (const float*)d_in[0];
  const float* Wq = (const float*)d_in[1];
  const float* bq = (const float*)d_in[2];
  const float* Wk = (const float*)d_in[3];
  const float* bk = (const float*)d_in[4];
  const float* Wv = (const float*)d_in[5];
  const float* bv = (const float*)d_in[6];
  const float* Wo = (const float*)d_in[7];
  const float* bo = (const float*)d_in[8];

  char* ws = (char*)d_ws;
  // xb is reused as ctx after the projection GEMMs are done reading it.
  unsigned short* xb  = (unsigned short*)(ws);                    // 16 MB
  unsigned short* wqb = (unsigned short*)(ws + (16ull << 20));    // 2 MB
  unsigned short* wkb = (unsigned short*)(ws + (18ull << 20));
  unsigned short* wvb = (unsigned short*)(ws + (20ull << 20));
  unsigned short* wob = (unsigned short*)(ws + (22ull << 20));
  unsigned short* Qb  = (unsigned short*)(ws + (24ull << 20));    // 16 MB
  unsigned short* Kb  = (unsigned short*)(ws + (40ull << 20));    // 16 MB
  unsigned short* VTb = (unsigned short*)(ws + (56ull << 20));    // 16 MB -> 72 MB total
  unsigned short* ctx = xb;

  cvt_f32_bf16<<<2048, 256, 0, stream>>>(x, xb, M_TOK * DM / 4);
  cvt_f32_bf16<<<512, 256, 0, stream>>>(Wq, wqb, DM * DM / 4);
  cvt_f32_bf16<<<512, 256, 0, stream>>>(Wk, wkb, DM * DM / 4);
  cvt_f32_bf16<<<512, 256, 0, stream>>>(Wv, wvb, DM * DM / 4);
  cvt_f32_bf16<<<512, 256, 0, stream>>>(Wo, wob, DM * DM / 4);

  dim3 gg(DM / BN, M_TOK / BM);
  gemm_bt<0><<<gg, 256, 0, stream>>>(xb, wqb, bq, Qb, M_TOK, DM, DM);
  gemm_bt<0><<<gg, 256, 0, stream>>>(xb, wkb, bk, Kb, M_TOK, DM, DM);
  gemm_bt<1><<<gg, 256, 0, stream>>>(xb, wvb, bv, VTb, M_TOK, DM, DM);

  dim3 ga(BATCH * NH, L_SEQ / QBLK);
  flash_attn<<<ga, 256, 0, stream>>>(Qb, Kb, VTb, ctx);

  gemm_bt<2><<<gg, 256, 0, stream>>>(ctx, wob, bo, d_out, M_TOK, DM, DM);
}

// Round 3
// 259.139 us; speedup vs baseline: 1.4754x; 1.4754x over previous
//
#include <hip/hip_runtime.h>
#include <stdint.h>

#define L_SEQ   2048
#define DM      1024
#define NH      16
#define DK      64
#define BATCH   4
#define M_TOK   (BATCH * L_SEQ)   // 8192

typedef __attribute__((ext_vector_type(8))) short bf16x8;
typedef __attribute__((ext_vector_type(4))) float f32x4;
typedef __attribute__((ext_vector_type(16))) float f32x16;
typedef __attribute__((ext_vector_type(4))) unsigned int u32x4;

typedef __attribute__((address_space(1))) void void_g;
typedef __attribute__((address_space(3))) void void_l;

#define EXP2F(x) __builtin_amdgcn_exp2f(x)

__device__ __forceinline__ unsigned short f2bf(float f) {
  unsigned int u = __builtin_bit_cast(unsigned int, f);
  u += 0x7FFFu + ((u >> 16) & 1u);
  return (unsigned short)(u >> 16);
}

// ---------------- fp32 -> bf16 convert (vectorized) ----------------
__global__ void cvt_f32_bf16(const float* __restrict__ src,
                             unsigned short* __restrict__ dst, int n4) {
  int i = blockIdx.x * blockDim.x + threadIdx.x;
  int stride = gridDim.x * blockDim.x;
  for (; i < n4; i += stride) {
    float4 v = ((const float4*)src)[i];
    ushort4 o;
    o.x = f2bf(v.x); o.y = f2bf(v.y); o.z = f2bf(v.z); o.w = f2bf(v.w);
    ((ushort4*)dst)[i] = o;
  }
}

// ---------------- bf16 GEMM: C = (A @ B^T + bias) * scale ----------------
#define BM 128
#define BN 128
#define BKK 32

template <int EPI>
__global__ __launch_bounds__(256) void gemm_bt(
    const unsigned short* __restrict__ A,
    const unsigned short* __restrict__ Bw,
    const float* __restrict__ bias, float scale,
    void* __restrict__ out, int M, int N, int K) {
  __shared__ unsigned short As[BM * BKK];
  __shared__ unsigned short Bs[BN * BKK];

  const int tidx = threadIdx.x;
  const int wid = tidx >> 6, lane = tidx & 63;
  const int wm = wid >> 1, wn = wid & 1;
  const int tm = blockIdx.y * BM, tn = blockIdx.x * BN;
  const int lr = lane & 15;
  const int lk = (lane >> 4) * 8;

  f32x4 acc[4][4];
#pragma unroll
  for (int m = 0; m < 4; ++m)
#pragma unroll
    for (int n = 0; n < 4; ++n) acc[m][n] = (f32x4)0.0f;

  for (int k0 = 0; k0 < K; k0 += BKK) {
#pragma unroll
    for (int j = 0; j < 2; ++j) {
      int e0 = (wid * 2 + j) * 512;
      int e = e0 + lane * 8;
      int r = e >> 5, c = e & 31;
      __builtin_amdgcn_global_load_lds(
          (const void_g*)(A + (size_t)(tm + r) * K + k0 + c),
          (void_l*)(As + e0), 16, 0, 0);
      __builtin_amdgcn_global_load_lds(
          (const void_g*)(Bw + (size_t)(tn + r) * K + k0 + c),
          (void_l*)(Bs + e0), 16, 0, 0);
    }
    __syncthreads();

    bf16x8 a[4], b[4];
#pragma unroll
    for (int m = 0; m < 4; ++m)
      a[m] = *(const bf16x8*)&As[(wm * 64 + m * 16 + lr) * BKK + lk];
#pragma unroll
    for (int n = 0; n < 4; ++n)
      b[n] = *(const bf16x8*)&Bs[(wn * 64 + n * 16 + lr) * BKK + lk];
#pragma unroll
    for (int m = 0; m < 4; ++m)
#pragma unroll
      for (int n = 0; n < 4; ++n)
        acc[m][n] = __builtin_amdgcn_mfma_f32_16x16x32_bf16(a[m], b[n], acc[m][n], 0, 0, 0);
    __syncthreads();
  }

#pragma unroll
  for (int m = 0; m < 4; ++m) {
    int row0 = tm + wm * 64 + m * 16 + (lane >> 4) * 4;
#pragma unroll
    for (int n = 0; n < 4; ++n) {
      int col = tn + wn * 64 + n * 16 + (lane & 15);
      float bc = bias[col];
#pragma unroll
      for (int jj = 0; jj < 4; ++jj) {
        float v = (acc[m][n][jj] + bc) * scale;
        int R = row0 + jj;
        if (EPI == 2) {
          ((float*)out)[(size_t)R * DM + col] = v;
        } else {
          int bb = R >> 11, ll = R & (L_SEQ - 1);
          int h = col >> 6, dd = col & 63;
          if (EPI == 0)
            ((unsigned short*)out)[(((size_t)bb * NH + h) * L_SEQ + ll) * DK + dd] = f2bf(v);
          else
            ((unsigned short*)out)[(((size_t)bb * NH + h) * DK + dd) * L_SEQ + ll] = f2bf(v);
        }
      }
    }
  }
}

// ---------------- flash attention: swapped 32x32 structure ----------------
// Q,K: [B,H,L,DK] bf16 (Q pre-scaled by 0.125*log2e). VT: [B,H,DK,L] bf16.
// ctx out: [B*L, DM] bf16.
#define KVB 64
#define LDK 68                 // row stride (elems): 34-dword rows -> <=2-way banks
#define NTILE (L_SEQ / KVB)
#define CLIP2 144.269504f      // 100*log2(e)
#define THR2  11.5415f         // 8*log2(e)

__device__ __forceinline__ bf16x8 lds_frag(const unsigned short* p) {
  uint2 a = *(const uint2*)p;        // elems 0..3 (b64)
  uint2 b = *(const uint2*)(p + 4);  // elems 4..7 (b64)
  u32x4 t = {a.x, a.y, b.x, b.y};
  return __builtin_bit_cast(bf16x8, t);
}

__device__ __forceinline__ void lds_st16(unsigned short* p, uint4 v) {
  *(uint2*)p = make_uint2(v.x, v.y);
  *(uint2*)(p + 4) = make_uint2(v.z, v.w);
}

// pack two f32 -> one dword of 2 bf16 (round-half-up; P>=0 so bias negligible)
__device__ __forceinline__ unsigned pack_bf16(float a, float b) {
  unsigned ua = __builtin_bit_cast(unsigned, a) + 0x8000u;
  unsigned ub = __builtin_bit_cast(unsigned, b) + 0x8000u;
  return __builtin_amdgcn_perm(ub, ua, 0x07060302u);
}

// a' = {a.lo32lanes, b.lo32lanes}; b' = {a.hi32lanes, b.hi32lanes}
__device__ __forceinline__ void pl32swap(unsigned& a, unsigned& b, int hi) {
  unsigned sa = (unsigned)__shfl_xor((int)a, 32);
  unsigned sb = (unsigned)__shfl_xor((int)b, 32);
  unsigned na = hi ? sb : a;
  unsigned nb = hi ? b : sa;
  a = na; b = nb;
}

#define MFMA32(a, b, c) __builtin_amdgcn_mfma_f32_32x32x16_bf16(a, b, c, 0, 0, 0)

__global__ __launch_bounds__(256, 2) void flash_attn(
    const unsigned short* __restrict__ Qg,
    const unsigned short* __restrict__ Kg,
    const unsigned short* __restrict__ VTg,
    unsigned short* __restrict__ ctx) {
  __shared__ unsigned short Ks[64 * LDK];
  __shared__ unsigned short Vs[64 * LDK];

  const int bh = blockIdx.x, b = bh >> 4, h = bh & 15;
  const int q0 = blockIdx.y * 256;
  const int tid = threadIdx.x;
  const int w = tid >> 6, lane = tid & 63;
  const int l31 = lane & 31, hi = lane >> 5;
  const size_t head = (size_t)bh * (L_SEQ * DK);

  const int srow = w * 16 + (lane >> 2);     // tile row this lane stages
  const int scol = (lane & 3) * 16;          // element col base

  // Q fragments: qf[qblock][kstep] ; B-frag layout row=lane&31, k=hi*8+j
  bf16x8 qf[2][4];
#pragma unroll
  for (int qq = 0; qq < 2; ++qq) {
    const unsigned short* qp = Qg + head + (size_t)(q0 + w * 64 + qq * 32 + l31) * DK + hi * 8;
#pragma unroll
    for (int ks = 0; ks < 4; ++ks)
      qf[qq][ks] = *(const bf16x8*)(qp + ks * 16);
  }

  f32x16 o[2][2];
#pragma unroll
  for (int qq = 0; qq < 2; ++qq)
#pragma unroll
    for (int jb = 0; jb < 2; ++jb) o[qq][jb] = (f32x16)0.0f;
  float mq[2] = {-1e30f, -1e30f}, lq[2] = {0.0f, 0.0f};

  uint4 kr0, kr1, vr0, vr1;
  { // prologue: stage tile 0
    const unsigned short* kp = Kg + head + (size_t)srow * DK + scol;
    kr0 = *(const uint4*)kp; kr1 = *(const uint4*)(kp + 8);
    const unsigned short* vp = VTg + head + (size_t)srow * L_SEQ + scol;
    vr0 = *(const uint4*)vp; vr1 = *(const uint4*)(vp + 8);
    lds_st16(Ks + srow * LDK + scol, kr0);
    lds_st16(Ks + srow * LDK + scol + 8, kr1);
    lds_st16(Vs + srow * LDK + scol, vr0);
    lds_st16(Vs + srow * LDK + scol + 8, vr1);
  }
  __syncthreads();

  for (int t = 0; t < NTILE; ++t) {
    // (a) issue next tile's global loads (latency hides under compute)
    if (t + 1 < NTILE) {
      const int kv0 = (t + 1) * KVB;
      const unsigned short* kp = Kg + head + (size_t)(kv0 + srow) * DK + scol;
      kr0 = *(const uint4*)kp; kr1 = *(const uint4*)(kp + 8);
      const unsigned short* vp = VTg + head + (size_t)srow * L_SEQ + kv0 + scol;
      vr0 = *(const uint4*)vp; vr1 = *(const uint4*)(vp + 8);
    }

    // (b) compute tile t from LDS
    bf16x8 kf[2][4];   // A-frags: K rows (kv), reused across both q-blocks
#pragma unroll
    for (int m = 0; m < 2; ++m)
#pragma unroll
      for (int ks = 0; ks < 4; ++ks)
        kf[m][ks] = lds_frag(Ks + (32 * m + l31) * LDK + ks * 16 + hi * 8);

    bf16x8 pa[2][4];
#pragma unroll
    for (int qq = 0; qq < 2; ++qq) {
      f32x16 s0 = (f32x16)0.0f, s1 = (f32x16)0.0f;   // S[kv][q], lane's q=32qq+l31
#pragma unroll
      for (int ks = 0; ks < 4; ++ks) {
        s0 = MFMA32(kf[0][ks], qf[qq][ks], s0);
        s1 = MFMA32(kf[1][ks], qf[qq][ks], s1);
      }
      // clip (log2-domain) + tile max
      float tmax = -1e30f;
#pragma unroll
      for (int r = 0; r < 16; ++r) {
        float a = fminf(fmaxf(s0[r], -CLIP2), CLIP2);
        float c = fminf(fmaxf(s1[r], -CLIP2), CLIP2);
        s0[r] = a; s1[r] = c;
        tmax = fmaxf(tmax, fmaxf(a, c));
      }
      tmax = fmaxf(tmax, __shfl_xor(tmax, 32));
      // defer-max (T13)
      if (!__all(tmax - mq[qq] <= THR2)) {
        float mn = fmaxf(mq[qq], tmax);
        float corr = EXP2F(mq[qq] - mn);
        lq[qq] *= corr;
#pragma unroll
        for (int r = 0; r < 16; ++r) { o[qq][0][r] *= corr; o[qq][1][r] *= corr; }
        mq[qq] = mn;
      }
      float ls = 0.0f;
#pragma unroll
      for (int r = 0; r < 16; ++r) {
        s0[r] = EXP2F(s0[r] - mq[qq]); ls += s0[r];
        s1[r] = EXP2F(s1[r] - mq[qq]); ls += s1[r];
      }
      ls += __shfl_xor(ls, 32);
      lq[qq] += ls;
      // pack P into PV B-fragments: frag[ks] elem j <- P[kv=16ks+8hi+j][q]
#pragma unroll
      for (int ks = 0; ks < 4; ++ks) {
        const int s8 = (ks & 1) * 8;
        const f32x16 sv = (ks < 2) ? s0 : s1;
        unsigned uA0 = pack_bf16(sv[s8 + 0], sv[s8 + 1]);
        unsigned uA1 = pack_bf16(sv[s8 + 2], sv[s8 + 3]);
        unsigned uB0 = pack_bf16(sv[s8 + 4], sv[s8 + 5]);
        unsigned uB1 = pack_bf16(sv[s8 + 6], sv[s8 + 7]);
        pl32swap(uA0, uB0, hi);   // -> frag dwords {0,2}
        pl32swap(uA1, uB1, hi);   // -> frag dwords {1,3}
        u32x4 tt = {uA0, uA1, uB0, uB1};
        pa[qq][ks] = __builtin_bit_cast(bf16x8, tt);
      }
    }

    // PV: O^T[d][q] += VT[d][kv] * P^T[q][kv]
#pragma unroll
    for (int jb = 0; jb < 2; ++jb)
#pragma unroll
      for (int ks = 0; ks < 4; ++ks) {
        bf16x8 vf = lds_frag(Vs + (32 * jb + l31) * LDK + ks * 16 + hi * 8);
        o[0][jb] = MFMA32(vf, pa[0][ks], o[0][jb]);
        o[1][jb] = MFMA32(vf, pa[1][ks], o[1][jb]);
      }

    __syncthreads();
    // (c) write staged regs -> LDS
    if (t + 1 < NTILE) {
      lds_st16(Ks + srow * LDK + scol, kr0);
      lds_st16(Ks + srow * LDK + scol + 8, kr1);
      lds_st16(Vs + srow * LDK + scol, vr0);
      lds_st16(Vs + srow * LDK + scol + 8, vr1);
    }
    __syncthreads();
  }

  // epilogue: normalize, write ctx[token, h*64+d]
#pragma unroll
  for (int qq = 0; qq < 2; ++qq) {
    float inv = 1.0f / lq[qq];
    const int tok = q0 + w * 64 + qq * 32 + l31;
    size_t base = ((size_t)b * L_SEQ + tok) * DM + h * DK;
#pragma unroll
    for (int jb = 0; jb < 2; ++jb)
#pragma unroll
      for (int c = 0; c < 4; ++c) {
        ushort4 pk;   // regs r=4c..4c+3 -> d = 32jb + 8c + 4hi + 0..3
        pk.x = f2bf(o[qq][jb][4 * c + 0] * inv);
        pk.y = f2bf(o[qq][jb][4 * c + 1] * inv);
        pk.z = f2bf(o[qq][jb][4 * c + 2] * inv);
        pk.w = f2bf(o[qq][jb][4 * c + 3] * inv);
        *(ushort4*)&ctx[base + jb * 32 + c * 8 + hi * 4] = pk;
      }
  }
}

// ---------------- launch ----------------
extern "C" void kernel_launch(void* const* d_in, const int* in_sizes, int n_in,
                              void* d_out, int out_size, void* d_ws, size_t ws_size,
                              hipStream_t stream) {
  (void)in_sizes; (void)n_in; (void)out_size; (void)ws_size;
  const float* x  = (const float*)d_in[0];
  const float* Wq = (const float*)d_in[1];
  const float* bq = (const float*)d_in[2];
  const float* Wk = (const float*)d_in[3];
  const float* bk = (const float*)d_in[4];
  const float* Wv = (const float*)d_in[5];
  const float* bv = (const float*)d_in[6];
  const float* Wo = (const float*)d_in[7];
  const float* bo = (const float*)d_in[8];

  char* ws = (char*)d_ws;
  unsigned short* xb  = (unsigned short*)(ws);                    // 16 MB
  unsigned short* wqb = (unsigned short*)(ws + (16ull << 20));
  unsigned short* wkb = (unsigned short*)(ws + (18ull << 20));
  unsigned short* wvb = (unsigned short*)(ws + (20ull << 20));
  unsigned short* wob = (unsigned short*)(ws + (22ull << 20));
  unsigned short* Qb  = (unsigned short*)(ws + (24ull << 20));
  unsigned short* Kb  = (unsigned short*)(ws + (40ull << 20));
  unsigned short* VTb = (unsigned short*)(ws + (56ull << 20));
  unsigned short* ctx = xb;

  cvt_f32_bf16<<<2048, 256, 0, stream>>>(x, xb, M_TOK * DM / 4);
  cvt_f32_bf16<<<512, 256, 0, stream>>>(Wq, wqb, DM * DM / 4);
  cvt_f32_bf16<<<512, 256, 0, stream>>>(Wk, wkb, DM * DM / 4);
  cvt_f32_bf16<<<512, 256, 0, stream>>>(Wv, wvb, DM * DM / 4);
  cvt_f32_bf16<<<512, 256, 0, stream>>>(Wo, wob, DM * DM / 4);

  dim3 gg(DM / BN, M_TOK / BM);
  // Q pre-scaled by 0.125 * log2(e): softmax runs in exp2 domain
  gemm_bt<0><<<gg, 256, 0, stream>>>(xb, wqb, bq, 0.1803368801f, Qb, M_TOK, DM, DM);
  gemm_bt<0><<<gg, 256, 0, stream>>>(xb, wkb, bk, 1.0f, Kb, M_TOK, DM, DM);
  gemm_bt<1><<<gg, 256, 0, stream>>>(xb, wvb, bv, 1.0f, VTb, M_TOK, DM, DM);

  dim3 ga(BATCH * NH, L_SEQ / 256);
  flash_attn<<<ga, 256, 0, stream>>>(Qb, Kb, VTb, ctx);

  gemm_bt<2><<<gg, 256, 0, stream>>>(ctx, wob, bo, 1.0f, d_out, M_TOK, DM, DM);
}